// Round 8
// baseline (706.064 us; speedup 1.0000x reference)
//
#include <hip/hip_runtime.h>
#include <hip/hip_fp16.h>

#define NB 512   // batch
#define NT 512   // time steps
#define NL 126   // labels
#define NS 128   // states (start=126, end=127)
#define SIGMA 0.015625f          // 2^-6 lagless-normalizer scale
#define LOG_INV_SIGMA 4.158883083f  // log 64

typedef _Float16 h2 __attribute__((ext_vector_type(2)));

static __device__ __forceinline__ int pk_from(float a, float b) {
  return __builtin_bit_cast(int, __builtin_amdgcn_cvt_pkrtz(a, b));
}
// guaranteed-packed fp16 ops on int-carried pairs
static __device__ __forceinline__ int pkmul(int a, int b) {
  int d; asm("v_pk_mul_f16 %0, %1, %2" : "=v"(d) : "v"(a), "v"(b)); return d;
}
static __device__ __forceinline__ int pkmax(int a, int b) {
  int d; asm("v_pk_max_f16 %0, %1, %2" : "=v"(d) : "v"(a), "v"(b)); return d;
}
static __device__ __forceinline__ int pkadd(int a, int b) {
  int d; asm("v_pk_add_f16 %0, %1, %2" : "=v"(d) : "v"(a), "v"(b)); return d;
}
// swap lane pairs (0<->1, 2<->3): quad_perm [1,0,3,2]
static __device__ __forceinline__ int dppswap(int x) {
  return __builtin_amdgcn_update_dpp(0, x, 0xB1, 0xf, 0xf, false);
}

// wave64 add-reduction to lane 63 (old=0 identity)
#define DPP_ADD(x, ctrl, rm) \
  ((x) + __int_as_float(__builtin_amdgcn_update_dpp(0, __float_as_int(x), (ctrl), (rm), 0xf, false)))
#define WAVE_ADD(x) do { \
  x = DPP_ADD(x, 0x111, 0xf); x = DPP_ADD(x, 0x112, 0xf); \
  x = DPP_ADD(x, 0x114, 0xf); x = DPP_ADD(x, 0x118, 0xf); \
  x = DPP_ADD(x, 0x142, 0xa); x = DPP_ADD(x, 0x143, 0xc); } while (0)

// 256 threads (4 waves) per batch element; lane pair owns one column.
// Z computed in-loop from the full v-read (lag-0, uniform, no reduce);
// S reduction deferred past the barrier (lag-2 bookkeeping).
__global__ __launch_bounds__(256) void crf_kernel(
    const float* __restrict__ emissions,   // [NB, NT, NL]
    const int*   __restrict__ labels,      // [NB, NT]
    const float* __restrict__ trans,       // [NS, NS]
    float*       __restrict__ out)
{
  const int b   = blockIdx.x;
  const int tid = threadIdx.x;
  const int wv  = tid >> 6;              // wave 0..3
  const int ln  = tid & 63;
  const int col = (wv << 5) | (ln >> 1); // column 0..127
  const int rh  = ln & 1;                // row half: rows [rh*64, rh*64+64)

  __shared__ __align__(16) _Float16 u_sh[2 * NS];   // ping-pong v buffers
  __shared__ __align__(16) float sPart[2][4];
  __shared__ float fin[8];

  const float* em  = emissions + (size_t)b * NT * NL;
  const int*   lab = labels + b * NT;

  // ---- per-column max tau (exact fp32) ----
  float tau = -3.0e38f;
  for (int i = 0; i < NS; i++) tau = fmaxf(tau, trans[i * NS + col]);

  // ---- tab[k] = rows (rh*64+2k, rh*64+2k+1) of exp(T[.][col]-tau) ----
  int tab[32];
  #pragma unroll
  for (int k = 0; k < 32; k++) {
    int row = rh * 64 + 2 * k;
    float t0 = __expf(trans[row * NS + col] - tau);
    float t1 = __expf(trans[(row + 1) * NS + col] - tau);
    tab[k] = pk_from(t0, t1);
  }

  // ---- gold path partial (2 timesteps per thread, distinct lanes) ----
  float realp = 0.f;
  #pragma unroll
  for (int q = 0; q < NT / 256; q++) {
    int t  = tid + q * 256;
    int lt = lab[t];
    int nx = (t + 1 < NT) ? lab[t + 1] : (NL + 1);
    realp += em[t * NL + lt] + trans[lt * NS + nx];
  }
  if (tid == 0) realp += trans[NL * NS + lab[0]];

  // ---- init: v = delta at start state, buffer 0 (Z(0) = 1) ----
  if (tid < NS) {
    u_sh[tid]      = (_Float16)((tid == NL) ? 1.f : 0.f);
    u_sh[NS + tid] = (_Float16)0.f;
  }
  float Q = 0.f, Cc = 0.f;
  float emc = (col < NL) ? em[col] : 0.f;        // rolling 2-deep prefetch
  float emn = (col < NL) ? em[NL + col] : 0.f;
  float cSprev = 0.f, vlast = 0.f;
  __syncthreads();

  for (int t = 0; t <= NT; t++) {
    // ---- deferred S-reduce of step t-1 (now post-barrier, off v-path) ----
    if (t > 0) {
      float cs = cSprev;
      WAVE_ADD(cs);
      if (ln == 63) sPart[(t - 1) & 1][wv] = cs;
    }
    // ---- consume S(t-2) (slot t&1), written pre-barrier(t-1) ----
    if (t >= 2) {
      const float4 sp = *(const float4*)sPart[t & 1];
      float S = 0.5f * ((sp.x + sp.y) + (sp.z + sp.w));  // 0.5: pair-dup
      Cc += __logf(S);
    }

    // ---- off-path: g = exp(obs + tau) from prefetched emission ----
    float obsv;
    if (t < NT) obsv = (col < NL) ? emc : -1000.f;
    else        obsv = (col == NL + 1) ? 0.f : -1000.f;
    float g = __expf(obsv + tau);
    emc = emn;
    emn = (t + 2 < NT && col < NL) ? em[(t + 2) * NL + col] : 0.f;

    // ---- critical path: 64 rows of column col + in-loop Z accumulation ----
    const int4* up = (const int4*)(u_sh + (t & 1) * NS) + rh * 8;
    int hA = 0, hB = 0, hC = 0, hD = 0;
    int sA = 0, sB = 0, sC = 0, sD = 0;
    int zA = 0, zB = 0;
    #pragma unroll
    for (int kk = 0; kk < 8; kk++) {
      int4 uu = up[kk];                // rows rh*64+8kk..+7
      zA = pkadd(zA, pkadd(uu.x, uu.y));
      zB = pkadd(zB, pkadd(uu.z, uu.w));
      int m0 = pkmul(uu.x, tab[4 * kk + 0]);
      int m1 = pkmul(uu.y, tab[4 * kk + 1]);
      int m2 = pkmul(uu.z, tab[4 * kk + 2]);
      int m3 = pkmul(uu.w, tab[4 * kk + 3]);
      hA = pkmax(hA, m0); hB = pkmax(hB, m1);
      hC = pkmax(hC, m2); hD = pkmax(hD, m3);
      sA = pkadd(sA, m0); sB = pkadd(sB, m1);
      sC = pkadd(sC, m2); sD = pkadd(sD, m3);
    }
    int hv = pkmax(pkmax(hA, hB), pkmax(hC, hD));
    int sv = pkadd(pkadd(sA, sB), pkadd(sC, sD));
    int zv = pkadd(zA, zB);
    hv = pkmax(hv, dppswap(hv));       // combine row halves across lane pair
    sv = pkadd(sv, dppswap(sv));
    zv = pkadd(zv, dppswap(zv));       // now Σ all 128 v's, identical in all lanes
    h2 hh = __builtin_bit_cast(h2, hv);
    h2 ss = __builtin_bit_cast(h2, sv);
    h2 zh = __builtin_bit_cast(h2, zv);
    float h = fmaxf(fmaxf((float)hh.x, (float)hh.y), 1e-30f);
    float s = (float)ss.x + (float)ss.y;
    float Z = fmaxf((float)zh.x + (float)zh.y, 1e-30f);

    // lag-0 uniform normalizer; bookkeeping logs the same Z it divides by
    float r = SIGMA * __builtin_amdgcn_rcpf(Z);
    Q += __logf(Z);

    float w = h * g;
    float v = w * r;
    vlast = v;
    u_sh[((t + 1) & 1) * NS + col] = (_Float16)v;

    cSprev = s * __builtin_amdgcn_rcpf(h);   // reduce deferred to next iter
    __syncthreads();                   // the ONLY barrier per step
  }

  // ---- flush S bookkeeping: steps NT-1 and NT ----
  {
    float cs = cSprev;                 // cS(NT)
    WAVE_ADD(cs);
    if (ln == 63) sPart[NT & 1][wv] = cs;
    const float4 sp = *(const float4*)sPart[(NT - 1) & 1];  // S(NT-1)
    float S = 0.5f * ((sp.x + sp.y) + (sp.z + sp.w));
    Cc += __logf(S);
  }
  // final-v sum (per-wave partials) and gold-path sum
  {
    float vf = vlast;
    WAVE_ADD(vf);
    WAVE_ADD(realp);
    if (ln == 63) { fin[wv] = vf; fin[4 + wv] = realp; }
  }
  __syncthreads();
  if (tid == 0) {
    const float4 sp = *(const float4*)sPart[NT & 1];        // S(NT)
    float S = 0.5f * ((sp.x + sp.y) + (sp.z + sp.w));
    float Cfin = Cc + __logf(S);
    float Zf = 0.5f * ((fin[0] + fin[1]) + (fin[2] + fin[3]));
    float realsum = (fin[4] + fin[5]) + (fin[6] + fin[7]);
    float total = Cfin + Q + 513.f * LOG_INV_SIGMA + __logf(Zf);
    atomicAdd(out, total - realsum);
  }
}

extern "C" void kernel_launch(void* const* d_in, const int* in_sizes, int n_in,
                              void* d_out, int out_size, void* d_ws, size_t ws_size,
                              hipStream_t stream) {
  const float* em  = (const float*)d_in[0];
  const int*   lab = (const int*)d_in[1];
  const float* tr  = (const float*)d_in[2];
  (void)hipMemsetAsync(d_out, 0, sizeof(float), stream);
  crf_kernel<<<NB, 256, 0, stream>>>(em, lab, tr, (float*)d_out);
}